// Round 3
// baseline (627.424 us; speedup 1.0000x reference)
//
#include <hip/hip_runtime.h>
#include <hip/hip_bf16.h>

// HGNN: out = BN(ReLU( segmax( BN(ReLU(concat(lf[li], dcoor) @ W1 + b1)) ) @ W2 + b2))
//   G[n,f]  = (last_features @ W1[:300] + b1)  as bf16 [N_last][320] padded (MFMA GEMM)
//   y[e,f]  = ReLU(G[li[e],f] + delta[e] . Wc[:,f])      (edge pass, 3 FMA/elem)
//   Edges counting-sorted by cur_idx -> segment-local running max in registers,
//   one atomicMax flush per segment boundary.
//   edge_pass v3: feature-pair threads (4B loads), 2 streams/block, UNR=16 with
//   A/B register double-buffer (rolling prefetch -> 16-32 loads in flight/thread).
//   BN1 affine a*y+c with sign(a)=sign(g1) known upfront; aggregate z=sgn*y via
//   order-preserving uint encoding; encoded-0 => empty segment => 0.
//   out_pre = ReLU(agg @ W2 + b2) -> d_out (MFMA GEMM, stats fused), affine in place.
// Workspace aliasing: region1 = Alf (bf16 A for gemm0) then zbuf[N_cur][320];
//                     region0 = Gb[N_last][320] then Ab2 (bf16 A for gemm1).

#define NPART 64
#define SB 256      // scan block
#define CH 256      // edges per edge_pass block
#define STR 128     // edges per stream (2 streams/block)
#define UNR 16      // edge_pass load batch depth (A/B double-buffered)

typedef __bf16 bf16_t;
typedef __bf16 bf16x4 __attribute__((ext_vector_type(4)));
typedef __bf16 bf16x8 __attribute__((ext_vector_type(8)));
typedef float f32x4 __attribute__((ext_vector_type(4)));

__device__ __forceinline__ unsigned enc_f32(float x) {
    unsigned u = __float_as_uint(x);
    return (u & 0x80000000u) ? ~u : (u | 0x80000000u);
}
__device__ __forceinline__ float dec_f32(unsigned e) {
    unsigned u = (e & 0x80000000u) ? (e & 0x7fffffffu) : ~e;
    return __uint_as_float(u);
}

// ---------- counting sort: hist -> scan -> scatter ----------
__global__ void hist_k(const int* __restrict__ ci, int E, int* __restrict__ hist)
{
    const int e = blockIdx.x * 256 + threadIdx.x;
    if (e < E) atomicAdd(&hist[ci[e]], 1);
}

__global__ void scan_reduce(const int* __restrict__ hist, int nseg, int* __restrict__ bsum)
{
    __shared__ int s[SB];
    const int tid = threadIdx.x;
    const int i = blockIdx.x * SB + tid;
    s[tid] = (i < nseg) ? hist[i] : 0;
    __syncthreads();
    for (int o = SB / 2; o > 0; o >>= 1) {
        if (tid < o) s[tid] += s[tid + o];
        __syncthreads();
    }
    if (tid == 0) bsum[blockIdx.x] = s[0];
}

__global__ void scan_top(int* __restrict__ bsum, int nb)
{
    __shared__ int s[SB];
    const int tid = threadIdx.x;
    const int v = (tid < nb) ? bsum[tid] : 0;
    s[tid] = v;
    __syncthreads();
    for (int o = 1; o < SB; o <<= 1) {
        int x = 0;
        if (tid >= o) x = s[tid - o];
        __syncthreads();
        s[tid] += x;
        __syncthreads();
    }
    if (tid < nb) bsum[tid] = s[tid] - v;   // exclusive
}

__global__ void scan_final(const int* __restrict__ hist, int nseg,
                           const int* __restrict__ bsum, int* __restrict__ cnt)
{
    __shared__ int s[SB];
    const int tid = threadIdx.x;
    const int i = blockIdx.x * SB + tid;
    const int v = (i < nseg) ? hist[i] : 0;
    s[tid] = v;
    __syncthreads();
    for (int o = 1; o < SB; o <<= 1) {
        int x = 0;
        if (tid >= o) x = s[tid - o];
        __syncthreads();
        s[tid] += x;
        __syncthreads();
    }
    if (i < nseg) cnt[i] = s[tid] - v + bsum[blockIdx.x];
}

__global__ void scatter_k(const int* __restrict__ ci, const int* __restrict__ li,
                          int E, int* __restrict__ cnt, int2* __restrict__ sorted)
{
    const int e = blockIdx.x * 256 + threadIdx.x;
    if (e >= E) return;
    const int c = ci[e];
    const int pos = atomicAdd(&cnt[c], 1);
    sorted[pos] = make_int2(li[e], c);
}

// ---------- pack W (fp32 [300][300] row-major) -> WT bf16 [384][320] = [n][k], zero-padded ----------
__global__ void pack_wt(const float* __restrict__ W, bf16_t* __restrict__ WT)
{
    const int idx = blockIdx.x * 256 + threadIdx.x;
    if (idx >= 384 * 320) return;
    const int n = idx / 320, k = idx % 320;
    float v = (n < 300 && k < 300) ? W[k * 300 + n] : 0.f;
    WT[idx] = (bf16_t)v;
}

// ---------- convert lf fp32 [M][300] -> bf16 [M][320] zero-padded ----------
__global__ void cvt_lf(const float* __restrict__ lf, bf16_t* __restrict__ out, int M)
{
    const int idx = blockIdx.x * 256 + threadIdx.x;   // one bf16x8 chunk each
    const int r = idx / 40, c8 = (idx % 40) * 8;
    if (r >= M) return;
    bf16x8 v = {};
    if (c8 + 8 <= 300) {
        const float4 a = *reinterpret_cast<const float4*>(&lf[(long)r * 300 + c8]);
        const float4 b = *reinterpret_cast<const float4*>(&lf[(long)r * 300 + c8 + 4]);
        v = (bf16x8){(bf16_t)a.x, (bf16_t)a.y, (bf16_t)a.z, (bf16_t)a.w,
                     (bf16_t)b.x, (bf16_t)b.y, (bf16_t)b.z, (bf16_t)b.w};
    } else if (c8 < 300) {   // c8 == 296
        const float4 a = *reinterpret_cast<const float4*>(&lf[(long)r * 300 + c8]);
        v[0] = (bf16_t)a.x; v[1] = (bf16_t)a.y; v[2] = (bf16_t)a.z; v[3] = (bf16_t)a.w;
    }
    *reinterpret_cast<bf16x8*>(&out[(long)r * 320 + c8]) = v;
}

// ---------- MFMA bf16 GEMM: C[M,:] = A[M,:300] @ W + bias ----------
// A bf16 [M][320] zero-padded; WT bf16 [384][320] = [n][k].
// Tiles: 128 (M) x 160 (N), BK=64; 4 waves in 2x2 (wave: 64 x 80).
// MODE 0: store bf16 [M][320] (pad cols zeroed) to outBF.
// MODE 1: ReLU, fp32 [M][300] to outF, stats partials.
template<int MODE>
__launch_bounds__(256)
__global__ void gemm_mfma(const bf16_t* __restrict__ A, int M,
                          const bf16_t* __restrict__ WT,
                          const float* __restrict__ bias,
                          bf16_t* __restrict__ outBF,
                          float* __restrict__ outF,
                          float* __restrict__ part)
{
    __shared__ bf16_t As[128][72];
    __shared__ bf16_t Bs[160][72];
    __shared__ float sSum[160], sSq[160];

    const int tid  = threadIdx.x;
    const int lane = tid & 63, wv = tid >> 6;
    const int wm = wv & 1, wn = wv >> 1;
    const int m0 = blockIdx.x * 128, n0 = blockIdx.y * 160;
    const int rl = lane & 15, quad = lane >> 4;

    if (MODE == 1 && tid < 160) { sSum[tid] = 0.f; sSq[tid] = 0.f; }

    f32x4 acc[4][5];
    #pragma unroll
    for (int i = 0; i < 4; ++i)
        #pragma unroll
        for (int j = 0; j < 5; ++j)
            acc[i][j] = (f32x4){0.f, 0.f, 0.f, 0.f};

    for (int k0 = 0; k0 < 320; k0 += 64) {
        // A tile: 128 rows x 64 k (bf16x8, clamped rows, no masks)
        #pragma unroll
        for (int i = 0; i < 4; ++i) {
            const int id = i * 256 + tid;
            const int r = id >> 3, kc = (id & 7) * 8;
            const int gr = min(m0 + r, M - 1);
            bf16x8 a8 = *reinterpret_cast<const bf16x8*>(&A[(long)gr * 320 + k0 + kc]);
            *reinterpret_cast<bf16x8*>(&As[r][kc]) = a8;
        }
        // B tile: 160 rows x 64 k
        #pragma unroll
        for (int i = 0; i < 5; ++i) {
            const int id = i * 256 + tid;
            const int n = id >> 3, kc = (id & 7) * 8;
            bf16x8 w8 = *reinterpret_cast<const bf16x8*>(&WT[(long)(n0 + n) * 320 + k0 + kc]);
            *reinterpret_cast<bf16x8*>(&Bs[n][kc]) = w8;
        }
        __syncthreads();

        #pragma unroll
        for (int kk = 0; kk < 2; ++kk) {
            const int kb = kk * 32 + quad * 8;
            bf16x8 af[4], bfr[5];
            #pragma unroll
            for (int mi = 0; mi < 4; ++mi)
                af[mi] = *reinterpret_cast<const bf16x8*>(&As[wm * 64 + mi * 16 + rl][kb]);
            #pragma unroll
            for (int nj = 0; nj < 5; ++nj)
                bfr[nj] = *reinterpret_cast<const bf16x8*>(&Bs[wn * 80 + nj * 16 + rl][kb]);
            #pragma unroll
            for (int mi = 0; mi < 4; ++mi)
                #pragma unroll
                for (int nj = 0; nj < 5; ++nj)
                    acc[mi][nj] = __builtin_amdgcn_mfma_f32_16x16x32_bf16(
                        af[mi], bfr[nj], acc[mi][nj], 0, 0, 0);
        }
        __syncthreads();
    }

    // epilogue: C/D layout col = lane&15, row = quad*4 + reg
    if (MODE == 0) {
        #pragma unroll
        for (int mi = 0; mi < 4; ++mi)
            #pragma unroll
            for (int nj = 0; nj < 5; ++nj)
                #pragma unroll
                for (int reg = 0; reg < 4; ++reg) {
                    const int r = m0 + wm * 64 + mi * 16 + quad * 4 + reg;
                    const int c = n0 + wn * 80 + nj * 16 + rl;   // < 320 by construction
                    if (r < M) {
                        const float v = (c < 300) ? (acc[mi][nj][reg] + bias[c]) : 0.f;
                        outBF[(long)r * 320 + c] = (bf16_t)v;
                    }
                }
    } else {
        float csum[5] = {}, csq[5] = {};
        #pragma unroll
        for (int mi = 0; mi < 4; ++mi)
            #pragma unroll
            for (int nj = 0; nj < 5; ++nj)
                #pragma unroll
                for (int reg = 0; reg < 4; ++reg) {
                    const int r = m0 + wm * 64 + mi * 16 + quad * 4 + reg;
                    const int c = n0 + wn * 80 + nj * 16 + rl;
                    if (r < M && c < 300) {
                        float v = fmaxf(acc[mi][nj][reg] + bias[c], 0.f);
                        outF[(long)r * 300 + c] = v;
                        csum[nj] += v; csq[nj] += v * v;
                    }
                }
        #pragma unroll
        for (int nj = 0; nj < 5; ++nj) {
            const int cl = wn * 80 + nj * 16 + rl;
            atomicAdd(&sSum[cl], csum[nj]);
            atomicAdd(&sSq[cl], csq[nj]);
        }
        __syncthreads();
        const int slot = (blockIdx.x + blockIdx.y * gridDim.x) & (NPART - 1);
        if (tid < 160 && (n0 + tid) < 300) {
            atomicAdd(&part[slot * 600 + n0 + tid], sSum[tid]);
            atomicAdd(&part[slot * 600 + 300 + n0 + tid], sSq[tid]);
        }
    }
}

// ---------- edge pass over SORTED edges: pair loads, 2 streams/block, A/B prefetch ----------
// Thread t: stream = t/160, feature pair ft = (t%160)*2. Each stream walks STR
// edges with register running-max; one atomicMax pair per segment boundary.
__launch_bounds__(320)
__global__ void edge_pass(const bf16_t* __restrict__ Gb,   // [N_last][320]
                          const float* __restrict__ last_coors,
                          const float* __restrict__ cur_coors,
                          const int2* __restrict__ sorted,  // (li, ci), sorted by ci
                          const float* __restrict__ Wc,     // rows 300..302 of W1, 3x300
                          const float* __restrict__ g1,
                          unsigned* __restrict__ zbuf,      // [N_cur][320], encoded, init 0
                          float* __restrict__ part1,
                          int E)
{
    __shared__ int sRow[CH], sCi[CH];
    __shared__ float sD0[CH], sD1[CH], sD2[CH];

    const int tid = threadIdx.x;
    const int e0 = blockIdx.x * CH;
    const int ecnt = min(CH, E - e0);

    for (int i = tid; i < ecnt; i += 320) {
        const int2 r = sorted[e0 + i];
        sRow[i] = r.x * 320;
        sCi[i]  = r.y;
        sD0[i] = last_coors[r.x * 3 + 0] - cur_coors[r.y * 3 + 0];
        sD1[i] = last_coors[r.x * 3 + 1] - cur_coors[r.y * 3 + 1];
        sD2[i] = last_coors[r.x * 3 + 2] - cur_coors[r.y * 3 + 2];
    }
    __syncthreads();

    const int stream = tid / 160;
    const int ft = (tid % 160) * 2;          // even; pair {ft, ft+1}
    const bool real = (ft < 300);
    float w00 = 0.f, w01 = 0.f, w10 = 0.f, w11 = 0.f, w20 = 0.f, w21 = 0.f;
    float sgn0 = 1.f, sgn1 = 1.f;
    if (real) {
        w00 = Wc[ft];        w01 = Wc[ft + 1];
        w10 = Wc[300 + ft];  w11 = Wc[300 + ft + 1];
        w20 = Wc[600 + ft];  w21 = Wc[600 + ft + 1];
        sgn0 = (g1[ft]     < 0.f) ? -1.f : 1.f;
        sgn1 = (g1[ft + 1] < 0.f) ? -1.f : 1.f;
    }

    const int ibeg = stream * STR;
    const int iend = min(ecnt, ibeg + STR);

    int cur = (ibeg < iend) ? sCi[ibeg] : 0;
    float m0 = -3.4e38f, m1 = -3.4e38f;
    float sum0 = 0.f, sq0 = 0.f, sum1 = 0.f, sq1 = 0.f;

    unsigned guA[UNR], guB[UNR];

    auto LOADB = [&](unsigned* g, int base) {
        #pragma unroll
        for (int j = 0; j < UNR; ++j)
            g[j] = *reinterpret_cast<const unsigned*>(&Gb[(long)sRow[base + j] + ft]);
    };
    auto CONSUME = [&](const unsigned* g, int base) {
        #pragma unroll
        for (int j = 0; j < UNR; ++j) {
            const int ci = sCi[base + j];
            if (ci != cur) {                   // stream-uniform branch
                if (real) {
                    atomicMax(&zbuf[(long)cur * 320 + ft],     enc_f32(m0));
                    atomicMax(&zbuf[(long)cur * 320 + ft + 1], enc_f32(m1));
                }
                cur = ci;
                m0 = -3.4e38f; m1 = -3.4e38f;
            }
            const float gx = __uint_as_float(g[j] << 16);
            const float gy = __uint_as_float(g[j] & 0xffff0000u);
            const float d0 = sD0[base + j], d1 = sD1[base + j], d2 = sD2[base + j];
            const float y0 = fmaxf(gx + d0 * w00 + d1 * w10 + d2 * w20, 0.f);
            const float y1 = fmaxf(gy + d0 * w01 + d1 * w11 + d2 * w21, 0.f);
            sum0 += y0; sq0 += y0 * y0; m0 = fmaxf(m0, sgn0 * y0);
            sum1 += y1; sq1 += y1 * y1; m1 = fmaxf(m1, sgn1 * y1);
        }
    };

    int i = ibeg;
    const int nfull = (iend - ibeg) / UNR;
    int b = 0;
    if (nfull > 0) LOADB(guA, i);
    while (b < nfull) {
        if (b + 1 < nfull) LOADB(guB, i + UNR);   // prefetch next while consuming
        CONSUME(guA, i);
        i += UNR; ++b;
        if (b >= nfull) break;
        if (b + 1 < nfull) LOADB(guA, i + UNR);
        CONSUME(guB, i);
        i += UNR; ++b;
    }
    for (; i < iend; ++i) {
        const int ci = sCi[i];
        if (ci != cur) {
            if (real) {
                atomicMax(&zbuf[(long)cur * 320 + ft],     enc_f32(m0));
                atomicMax(&zbuf[(long)cur * 320 + ft + 1], enc_f32(m1));
            }
            cur = ci;
            m0 = -3.4e38f; m1 = -3.4e38f;
        }
        const unsigned gu = *reinterpret_cast<const unsigned*>(&Gb[(long)sRow[i] + ft]);
        const float gx = __uint_as_float(gu << 16);
        const float gy = __uint_as_float(gu & 0xffff0000u);
        const float d0 = sD0[i], d1 = sD1[i], d2 = sD2[i];
        const float y0 = fmaxf(gx + d0 * w00 + d1 * w10 + d2 * w20, 0.f);
        const float y1 = fmaxf(gy + d0 * w01 + d1 * w11 + d2 * w21, 0.f);
        sum0 += y0; sq0 += y0 * y0; m0 = fmaxf(m0, sgn0 * y0);
        sum1 += y1; sq1 += y1 * y1; m1 = fmaxf(m1, sgn1 * y1);
    }
    if (real && ibeg < iend) {
        atomicMax(&zbuf[(long)cur * 320 + ft],     enc_f32(m0));
        atomicMax(&zbuf[(long)cur * 320 + ft + 1], enc_f32(m1));
    }

    const int slot = blockIdx.x & (NPART - 1);
    if (real) {
        atomicAdd(&part1[slot * 600 + ft],           sum0);
        atomicAdd(&part1[slot * 600 + ft + 1],       sum1);
        atomicAdd(&part1[slot * 600 + 300 + ft],     sq0);
        atomicAdd(&part1[slot * 600 + 300 + ft + 1], sq1);
    }
}

// ---------- reduce partials -> per-feature affine (a, c) ----------
__global__ void stats_finalize(const float* __restrict__ part,
                               const float* __restrict__ g,
                               const float* __restrict__ be,
                               float invCnt, float* __restrict__ ac)
{
    const int t = threadIdx.x;
    if (t >= 300) return;
    float sum = 0.f, sq = 0.f;
    for (int p = 0; p < NPART; ++p) {
        sum += part[p * 600 + t];
        sq  += part[p * 600 + 300 + t];
    }
    const float mean = sum * invCnt;
    const float var = fmaxf(sq * invCnt - mean * mean, 0.f);
    const float inv = rsqrtf(var + 1e-5f);
    const float a = g[t] * inv;
    ac[t] = a;
    ac[300 + t] = be[t] - mean * a;
}

// ---------- decode zbuf -> Ab2 bf16 [N_cur][320] zero-padded ----------
__global__ void agg_finalize(const unsigned* __restrict__ zbuf,
                             const float* __restrict__ ac1,
                             bf16_t* __restrict__ Ab2)
{
    const int t = threadIdx.x;   // 320 threads
    float v = 0.f;
    if (t < 300) {
        const unsigned u = zbuf[(long)blockIdx.x * 320 + t];
        if (u != 0u) v = fabsf(ac1[t]) * dec_f32(u) + ac1[300 + t];
    }
    Ab2[(long)blockIdx.x * 320 + t] = (bf16_t)v;
}

// ---------- apply BN2 affine to d_out in place ----------
__global__ void finalize_out(float* __restrict__ out,
                             const float* __restrict__ ac2)
{
    const int t = threadIdx.x;
    if (t >= 300) return;
    const long i = (long)blockIdx.x * 300 + t;
    out[i] = ac2[t] * out[i] + ac2[300 + t];
}

extern "C" void kernel_launch(void* const* d_in, const int* in_sizes, int n_in,
                              void* d_out, int out_size, void* d_ws, size_t ws_size,
                              hipStream_t stream)
{
    const float* last_coors    = (const float*)d_in[0];
    const float* last_features = (const float*)d_in[1];
    const float* cur_coors     = (const float*)d_in[2];
    const int*   cur_idx       = (const int*)d_in[3];
    const int*   last_idx      = (const int*)d_in[4];
    const float* W1  = (const float*)d_in[5];
    const float* b1  = (const float*)d_in[6];
    const float* g1  = (const float*)d_in[7];
    const float* be1 = (const float*)d_in[8];
    const float* W2  = (const float*)d_in[9];
    const float* b2  = (const float*)d_in[10];
    const float* g2  = (const float*)d_in[11];
    const float* be2 = (const float*)d_in[12];
    float* out = (float*)d_out;

    const int N_last = in_sizes[0] / 3;
    const int N_cur  = in_sizes[2] / 3;
    const int E      = in_sizes[3];

    const int nb1 = (N_cur + SB - 1) / SB;

    // ---- workspace (aliased regions) ----
    char* ws = (char*)d_ws;
    size_t off = 0;
    // region0: Gb (N_last x 320 bf16) -> later Ab2 (N_cur x 320 bf16)
    const size_t sz_r0 = (size_t)N_last * 320 * 2;
    bf16_t* Gb  = (bf16_t*)(ws + off);
    bf16_t* Ab2 = (bf16_t*)(ws + off);
    off += sz_r0; off = (off + 255) & ~(size_t)255;
    // region1: Alf (N_last x 320 bf16) -> later zbuf (N_cur x 320 u32)
    const size_t sz_alf = (size_t)N_last * 320 * 2;
    const size_t sz_zb  = (size_t)N_cur * 320 * 4;
    bf16_t* Alf = (bf16_t*)(ws + off);
    unsigned* zbuf = (unsigned*)(ws + off);
    off += (sz_alf > sz_zb ? sz_alf : sz_zb); off = (off + 255) & ~(size_t)255;
    int2* sorted = (int2*)(ws + off);  off += (size_t)E * 8;
    int* hist = (int*)(ws + off);      off += (size_t)nb1 * SB * 4;
    int* cnt  = (int*)(ws + off);      off += (size_t)nb1 * SB * 4;
    int* bsum = (int*)(ws + off);      off += 256 * 4;
    bf16_t* WT1 = (bf16_t*)(ws + off); off += (size_t)384 * 320 * 2;
    bf16_t* WT2 = (bf16_t*)(ws + off); off += (size_t)384 * 320 * 2;
    float* part1 = (float*)(ws + off); off += (size_t)NPART * 600 * 4;
    float* part2 = (float*)(ws + off); off += (size_t)NPART * 600 * 4;
    float* ac1   = (float*)(ws + off); off += 600 * 4;
    float* ac2   = (float*)(ws + off); off += 600 * 4;

    hipMemsetAsync(hist, 0, (size_t)nb1 * SB * 4, stream);
    hipMemsetAsync(part1, 0, (size_t)NPART * 600 * 4, stream);
    hipMemsetAsync(part2, 0, (size_t)NPART * 600 * 4, stream);

    // ---- counting sort of edges by cur_idx (independent of regions 0/1) ----
    hist_k<<<(E + 255) / 256, 256, 0, stream>>>(cur_idx, E, hist);
    scan_reduce<<<nb1, SB, 0, stream>>>(hist, N_cur, bsum);
    scan_top<<<1, SB, 0, stream>>>(bsum, nb1);
    scan_final<<<nb1, SB, 0, stream>>>(hist, N_cur, bsum, cnt);
    scatter_k<<<(E + 255) / 256, 256, 0, stream>>>(cur_idx, last_idx, E, cnt, sorted);

    // ---- weights + A conversion ----
    pack_wt<<<480, 256, 0, stream>>>(W1, WT1);
    pack_wt<<<480, 256, 0, stream>>>(W2, WT2);
    cvt_lf<<<((N_last * 40) + 255) / 256, 256, 0, stream>>>(last_features, Alf, N_last);

    // G = last_features @ W1[:300] + b1  (bf16 MFMA; reads Alf, writes Gb [M][320])
    dim3 gridG((N_last + 127) / 128, 2);
    gemm_mfma<0><<<gridG, 256, 0, stream>>>(Alf, N_last, WT1, b1, Gb, nullptr, nullptr);

    // zbuf overwrites Alf (stream-ordered after gemm0)
    hipMemsetAsync(zbuf, 0, sz_zb, stream);

    // edge pass over sorted edges
    const int nEB = (E + CH - 1) / CH;
    edge_pass<<<nEB, 320, 0, stream>>>(Gb, last_coors, cur_coors, sorted,
                                       W1 + 300 * 300, g1, zbuf, part1, E);

    stats_finalize<<<1, 320, 0, stream>>>(part1, g1, be1, 1.0f / (float)E, ac1);
    // Ab2 overwrites Gb (Gb consumed by edge_pass)
    agg_finalize<<<N_cur, 320, 0, stream>>>(zbuf, ac1, Ab2);

    // out_pre = ReLU(agg @ W2 + b2), stats2 partials (bf16 MFMA)
    dim3 grid2((N_cur + 127) / 128, 2);
    gemm_mfma<1><<<grid2, 256, 0, stream>>>(Ab2, N_cur, WT2, b2, nullptr, out, part2);

    stats_finalize<<<1, 320, 0, stream>>>(part2, g2, be2, 1.0f / (float)N_cur, ac2);
    finalize_out<<<N_cur, 320, 0, stream>>>(out, ac2);
}

// Round 4
// 586.340 us; speedup vs baseline: 1.0701x; 1.0701x over previous
//
#include <hip/hip_runtime.h>
#include <hip/hip_bf16.h>

// HGNN: out = BN(ReLU( segmax( BN(ReLU(concat(lf[li], dcoor) @ W1 + b1)) ) @ W2 + b2))
//   G[n,f]  = (last_features @ W1[:300] + b1)  as bf16 [N_last][320] padded (MFMA GEMM)
//   y[e,f]  = ReLU(G[li[e],f] + delta[e] . Wc[:,f])      (edge pass, 3 FMA/elem)
//   Edges counting-sorted by cur_idx; block OWNS a contiguous range of SEGB
//   segments (2 wave-group streams x SEGB/2 each), so segment running-max
//   flushes are PLAIN STORES (no global atomics, no cross-XCD RMW).
//   BN1 affine a*y+c with sign(a)=sign(g1) known upfront; aggregate z=sgn*y via
//   order-preserving uint encoding; encoded-0 => empty segment => 0.
//   out_pre = ReLU(agg @ W2 + b2) -> d_out (MFMA GEMM, stats fused), affine in place.
// Workspace aliasing: region1 = Alf (bf16 A for gemm0) then zbuf[N_cur][320];
//                     region0 = Gb[N_last][320] then Ab2 (bf16 A for gemm1).

#define NPART 64
#define SB 256      // scan block
#define SEGB 32     // cur segments owned per edge_pass block (2 streams x 16)
#define CHS 256     // staged edges per stream chunk
#define UNR 8       // edge_pass load batch depth (single buffer)

typedef __bf16 bf16_t;
typedef __bf16 bf16x4 __attribute__((ext_vector_type(4)));
typedef __bf16 bf16x8 __attribute__((ext_vector_type(8)));
typedef float f32x4 __attribute__((ext_vector_type(4)));

__device__ __forceinline__ unsigned enc_f32(float x) {
    unsigned u = __float_as_uint(x);
    return (u & 0x80000000u) ? ~u : (u | 0x80000000u);
}
__device__ __forceinline__ float dec_f32(unsigned e) {
    unsigned u = (e & 0x80000000u) ? (e & 0x7fffffffu) : ~e;
    return __uint_as_float(u);
}

// ---------- counting sort: hist -> scan -> scatter ----------
__global__ void hist_k(const int* __restrict__ ci, int E, int* __restrict__ hist)
{
    const int e = blockIdx.x * 256 + threadIdx.x;
    if (e < E) atomicAdd(&hist[ci[e]], 1);
}

__global__ void scan_reduce(const int* __restrict__ hist, int nseg, int* __restrict__ bsum)
{
    __shared__ int s[SB];
    const int tid = threadIdx.x;
    const int i = blockIdx.x * SB + tid;
    s[tid] = (i < nseg) ? hist[i] : 0;
    __syncthreads();
    for (int o = SB / 2; o > 0; o >>= 1) {
        if (tid < o) s[tid] += s[tid + o];
        __syncthreads();
    }
    if (tid == 0) bsum[blockIdx.x] = s[0];
}

__global__ void scan_top(int* __restrict__ bsum, int nb)
{
    __shared__ int s[SB];
    const int tid = threadIdx.x;
    const int v = (tid < nb) ? bsum[tid] : 0;
    s[tid] = v;
    __syncthreads();
    for (int o = 1; o < SB; o <<= 1) {
        int x = 0;
        if (tid >= o) x = s[tid - o];
        __syncthreads();
        s[tid] += x;
        __syncthreads();
    }
    if (tid < nb) bsum[tid] = s[tid] - v;   // exclusive
}

__global__ void scan_final(const int* __restrict__ hist, int nseg,
                           const int* __restrict__ bsum, int* __restrict__ cnt)
{
    __shared__ int s[SB];
    const int tid = threadIdx.x;
    const int i = blockIdx.x * SB + tid;
    const int v = (i < nseg) ? hist[i] : 0;
    s[tid] = v;
    __syncthreads();
    for (int o = 1; o < SB; o <<= 1) {
        int x = 0;
        if (tid >= o) x = s[tid - o];
        __syncthreads();
        s[tid] += x;
        __syncthreads();
    }
    if (i < nseg) cnt[i] = s[tid] - v + bsum[blockIdx.x];
}

__global__ void scatter_k(const int* __restrict__ ci, const int* __restrict__ li,
                          int E, int* __restrict__ cnt, int2* __restrict__ sorted)
{
    const int e = blockIdx.x * 256 + threadIdx.x;
    if (e >= E) return;
    const int c = ci[e];
    const int pos = atomicAdd(&cnt[c], 1);
    sorted[pos] = make_int2(li[e], c);
    // after this kernel: cnt[c] = END offset of segment c in sorted[]
}

// ---------- pack W (fp32 [300][300] row-major) -> WT bf16 [384][320] = [n][k], zero-padded ----------
__global__ void pack_wt(const float* __restrict__ W, bf16_t* __restrict__ WT)
{
    const int idx = blockIdx.x * 256 + threadIdx.x;
    if (idx >= 384 * 320) return;
    const int n = idx / 320, k = idx % 320;
    float v = (n < 300 && k < 300) ? W[k * 300 + n] : 0.f;
    WT[idx] = (bf16_t)v;
}

// ---------- convert lf fp32 [M][300] -> bf16 [M][320] zero-padded ----------
__global__ void cvt_lf(const float* __restrict__ lf, bf16_t* __restrict__ out, int M)
{
    const int idx = blockIdx.x * 256 + threadIdx.x;   // one bf16x8 chunk each
    const int r = idx / 40, c8 = (idx % 40) * 8;
    if (r >= M) return;
    bf16x8 v = {};
    if (c8 + 8 <= 300) {
        const float4 a = *reinterpret_cast<const float4*>(&lf[(long)r * 300 + c8]);
        const float4 b = *reinterpret_cast<const float4*>(&lf[(long)r * 300 + c8 + 4]);
        v = (bf16x8){(bf16_t)a.x, (bf16_t)a.y, (bf16_t)a.z, (bf16_t)a.w,
                     (bf16_t)b.x, (bf16_t)b.y, (bf16_t)b.z, (bf16_t)b.w};
    } else if (c8 < 300) {   // c8 == 296
        const float4 a = *reinterpret_cast<const float4*>(&lf[(long)r * 300 + c8]);
        v[0] = (bf16_t)a.x; v[1] = (bf16_t)a.y; v[2] = (bf16_t)a.z; v[3] = (bf16_t)a.w;
    }
    *reinterpret_cast<bf16x8*>(&out[(long)r * 320 + c8]) = v;
}

// ---------- MFMA bf16 GEMM: C[M,:] = A[M,:300] @ W + bias ----------
// A bf16 [M][320] zero-padded; WT bf16 [384][320] = [n][k].
// Tiles: 128 (M) x 160 (N), BK=64; 4 waves in 2x2 (wave: 64 x 80).
// MODE 0: store bf16 [M][320] (pad cols zeroed) to outBF.
// MODE 1: ReLU, fp32 [M][300] to outF, stats partials.
template<int MODE>
__launch_bounds__(256)
__global__ void gemm_mfma(const bf16_t* __restrict__ A, int M,
                          const bf16_t* __restrict__ WT,
                          const float* __restrict__ bias,
                          bf16_t* __restrict__ outBF,
                          float* __restrict__ outF,
                          float* __restrict__ part)
{
    __shared__ bf16_t As[128][72];
    __shared__ bf16_t Bs[160][72];
    __shared__ float sSum[160], sSq[160];

    const int tid  = threadIdx.x;
    const int lane = tid & 63, wv = tid >> 6;
    const int wm = wv & 1, wn = wv >> 1;
    const int m0 = blockIdx.x * 128, n0 = blockIdx.y * 160;
    const int rl = lane & 15, quad = lane >> 4;

    if (MODE == 1 && tid < 160) { sSum[tid] = 0.f; sSq[tid] = 0.f; }

    f32x4 acc[4][5];
    #pragma unroll
    for (int i = 0; i < 4; ++i)
        #pragma unroll
        for (int j = 0; j < 5; ++j)
            acc[i][j] = (f32x4){0.f, 0.f, 0.f, 0.f};

    for (int k0 = 0; k0 < 320; k0 += 64) {
        // A tile: 128 rows x 64 k (bf16x8, clamped rows, no masks)
        #pragma unroll
        for (int i = 0; i < 4; ++i) {
            const int id = i * 256 + tid;
            const int r = id >> 3, kc = (id & 7) * 8;
            const int gr = min(m0 + r, M - 1);
            bf16x8 a8 = *reinterpret_cast<const bf16x8*>(&A[(long)gr * 320 + k0 + kc]);
            *reinterpret_cast<bf16x8*>(&As[r][kc]) = a8;
        }
        // B tile: 160 rows x 64 k
        #pragma unroll
        for (int i = 0; i < 5; ++i) {
            const int id = i * 256 + tid;
            const int n = id >> 3, kc = (id & 7) * 8;
            bf16x8 w8 = *reinterpret_cast<const bf16x8*>(&WT[(long)(n0 + n) * 320 + k0 + kc]);
            *reinterpret_cast<bf16x8*>(&Bs[n][kc]) = w8;
        }
        __syncthreads();

        #pragma unroll
        for (int kk = 0; kk < 2; ++kk) {
            const int kb = kk * 32 + quad * 8;
            bf16x8 af[4], bfr[5];
            #pragma unroll
            for (int mi = 0; mi < 4; ++mi)
                af[mi] = *reinterpret_cast<const bf16x8*>(&As[wm * 64 + mi * 16 + rl][kb]);
            #pragma unroll
            for (int nj = 0; nj < 5; ++nj)
                bfr[nj] = *reinterpret_cast<const bf16x8*>(&Bs[wn * 80 + nj * 16 + rl][kb]);
            #pragma unroll
            for (int mi = 0; mi < 4; ++mi)
                #pragma unroll
                for (int nj = 0; nj < 5; ++nj)
                    acc[mi][nj] = __builtin_amdgcn_mfma_f32_16x16x32_bf16(
                        af[mi], bfr[nj], acc[mi][nj], 0, 0, 0);
        }
        __syncthreads();
    }

    // epilogue: C/D layout col = lane&15, row = quad*4 + reg
    if (MODE == 0) {
        #pragma unroll
        for (int mi = 0; mi < 4; ++mi)
            #pragma unroll
            for (int nj = 0; nj < 5; ++nj)
                #pragma unroll
                for (int reg = 0; reg < 4; ++reg) {
                    const int r = m0 + wm * 64 + mi * 16 + quad * 4 + reg;
                    const int c = n0 + wn * 80 + nj * 16 + rl;   // < 320 by construction
                    if (r < M) {
                        const float v = (c < 300) ? (acc[mi][nj][reg] + bias[c]) : 0.f;
                        outBF[(long)r * 320 + c] = (bf16_t)v;
                    }
                }
    } else {
        float csum[5] = {}, csq[5] = {};
        #pragma unroll
        for (int mi = 0; mi < 4; ++mi)
            #pragma unroll
            for (int nj = 0; nj < 5; ++nj)
                #pragma unroll
                for (int reg = 0; reg < 4; ++reg) {
                    const int r = m0 + wm * 64 + mi * 16 + quad * 4 + reg;
                    const int c = n0 + wn * 80 + nj * 16 + rl;
                    if (r < M && c < 300) {
                        float v = fmaxf(acc[mi][nj][reg] + bias[c], 0.f);
                        outF[(long)r * 300 + c] = v;
                        csum[nj] += v; csq[nj] += v * v;
                    }
                }
        #pragma unroll
        for (int nj = 0; nj < 5; ++nj) {
            const int cl = wn * 80 + nj * 16 + rl;
            atomicAdd(&sSum[cl], csum[nj]);
            atomicAdd(&sSq[cl], csq[nj]);
        }
        __syncthreads();
        const int slot = (blockIdx.x + blockIdx.y * gridDim.x) & (NPART - 1);
        if (tid < 160 && (n0 + tid) < 300) {
            atomicAdd(&part[slot * 600 + n0 + tid], sSum[tid]);
            atomicAdd(&part[slot * 600 + 300 + n0 + tid], sSq[tid]);
        }
    }
}

// ---------- edge pass: block owns SEGB contiguous segments; NO global atomics ----------
// 320 threads = 2 streams x 160 feature-pair threads. Stream st owns segments
// [g0 + st*SEGB/2, ...), i.e. a contiguous sorted edge slice; running max per
// segment flushed with a plain store to zbuf.
__launch_bounds__(320)
__global__ void edge_pass(const bf16_t* __restrict__ Gb,   // [N_last][320]
                          const float* __restrict__ last_coors,
                          const float* __restrict__ cur_coors,
                          const int2* __restrict__ sorted,  // (li, ci), sorted by ci
                          const int*  __restrict__ segEnd,  // end offsets per cur node
                          const float* __restrict__ Wc,     // rows 300..302 of W1, 3x300
                          const float* __restrict__ g1,
                          unsigned* __restrict__ zbuf,      // [N_cur][320], encoded, init 0
                          float* __restrict__ part1,
                          int N_cur)
{
    __shared__ int sRow[2][CHS], sCi[2][CHS];
    __shared__ float sD0[2][CHS], sD1[2][CHS], sD2[2][CHS];

    const int tid = threadIdx.x;
    const int st  = (tid >= 160) ? 1 : 0;
    const int ts  = tid - st * 160;          // 0..159 within stream

    const int g0   = blockIdx.x * SEGB;
    const int gEnd = min(g0 + SEGB, N_cur);
    const int gMid = min(g0 + SEGB / 2, gEnd);

    const int e00 = (g0   == 0) ? 0 : segEnd[g0 - 1];
    const int e01 = (gMid == 0) ? 0 : segEnd[gMid - 1];
    const int e11 = (gEnd == 0) ? 0 : segEnd[gEnd - 1];

    const int ebeg = st ? e01 : e00;
    const int eend = st ? e11 : e01;

    const int nch0 = (e01 - e00 + CHS - 1) / CHS;
    const int nch1 = (e11 - e01 + CHS - 1) / CHS;
    const int nch  = max(nch0, nch1);

    const int ft = ts * 2;                   // feature pair {ft, ft+1}, ft<=318
    const bool real = (ft < 300);
    float w00 = 0.f, w01 = 0.f, w10 = 0.f, w11 = 0.f, w20 = 0.f, w21 = 0.f;
    float sgn0 = 1.f, sgn1 = 1.f;
    if (real) {
        w00 = Wc[ft];        w01 = Wc[ft + 1];
        w10 = Wc[300 + ft];  w11 = Wc[300 + ft + 1];
        w20 = Wc[600 + ft];  w21 = Wc[600 + ft + 1];
        sgn0 = (g1[ft]     < 0.f) ? -1.f : 1.f;
        sgn1 = (g1[ft + 1] < 0.f) ? -1.f : 1.f;
    }

    int cur = -1;                            // -1 = no open segment
    float m0 = -3.4e38f, m1 = -3.4e38f;
    float sum0 = 0.f, sq0 = 0.f, sum1 = 0.f, sq1 = 0.f;

    for (int ch = 0; ch < nch; ++ch) {
        const int cbeg = ebeg + ch * CHS;
        const int ccnt = min(CHS, eend - cbeg);   // may be <= 0

        // stage this stream's chunk (160 threads -> up to CHS edges)
        for (int i = ts; i < ccnt; i += 160) {
            const int2 r = sorted[cbeg + i];
            sRow[st][i] = r.x * 320;
            sCi[st][i]  = r.y;
            sD0[st][i] = last_coors[r.x * 3 + 0] - cur_coors[r.y * 3 + 0];
            sD1[st][i] = last_coors[r.x * 3 + 1] - cur_coors[r.y * 3 + 1];
            sD2[st][i] = last_coors[r.x * 3 + 2] - cur_coors[r.y * 3 + 2];
        }
        __syncthreads();

        int i = 0;
        for (; i + UNR <= ccnt; i += UNR) {
            unsigned gu[UNR];
            #pragma unroll
            for (int j = 0; j < UNR; ++j)
                gu[j] = *reinterpret_cast<const unsigned*>(&Gb[(long)sRow[st][i + j] + ft]);
            #pragma unroll
            for (int j = 0; j < UNR; ++j) {
                const int ci = sCi[st][i + j];
                if (ci != cur) {               // stream-uniform branch
                    if (cur >= 0) {            // plain store: block owns the segment
                        zbuf[(long)cur * 320 + ft]     = enc_f32(m0);
                        zbuf[(long)cur * 320 + ft + 1] = enc_f32(m1);
                    }
                    cur = ci;
                    m0 = -3.4e38f; m1 = -3.4e38f;
                }
                const float gx = __uint_as_float(gu[j] << 16);
                const float gy = __uint_as_float(gu[j] & 0xffff0000u);
                const float d0 = sD0[st][i + j], d1 = sD1[st][i + j], d2 = sD2[st][i + j];
                const float y0 = fmaxf(gx + d0 * w00 + d1 * w10 + d2 * w20, 0.f);
                const float y1 = fmaxf(gy + d0 * w01 + d1 * w11 + d2 * w21, 0.f);
                sum0 += y0; sq0 += y0 * y0; m0 = fmaxf(m0, sgn0 * y0);
                sum1 += y1; sq1 += y1 * y1; m1 = fmaxf(m1, sgn1 * y1);
            }
        }
        for (; i < ccnt; ++i) {
            const int ci = sCi[st][i];
            if (ci != cur) {
                if (cur >= 0) {
                    zbuf[(long)cur * 320 + ft]     = enc_f32(m0);
                    zbuf[(long)cur * 320 + ft + 1] = enc_f32(m1);
                }
                cur = ci;
                m0 = -3.4e38f; m1 = -3.4e38f;
            }
            const unsigned gu = *reinterpret_cast<const unsigned*>(&Gb[(long)sRow[st][i] + ft]);
            const float gx = __uint_as_float(gu << 16);
            const float gy = __uint_as_float(gu & 0xffff0000u);
            const float d0 = sD0[st][i], d1 = sD1[st][i], d2 = sD2[st][i];
            const float y0 = fmaxf(gx + d0 * w00 + d1 * w10 + d2 * w20, 0.f);
            const float y1 = fmaxf(gy + d0 * w01 + d1 * w11 + d2 * w21, 0.f);
            sum0 += y0; sq0 += y0 * y0; m0 = fmaxf(m0, sgn0 * y0);
            sum1 += y1; sq1 += y1 * y1; m1 = fmaxf(m1, sgn1 * y1);
        }
        __syncthreads();   // protect LDS before next chunk's staging
    }
    if (cur >= 0) {        // flush last open segment
        zbuf[(long)cur * 320 + ft]     = enc_f32(m0);
        zbuf[(long)cur * 320 + ft + 1] = enc_f32(m1);
    }

    const int slot = blockIdx.x & (NPART - 1);
    if (real) {
        atomicAdd(&part1[slot * 600 + ft],           sum0);
        atomicAdd(&part1[slot * 600 + ft + 1],       sum1);
        atomicAdd(&part1[slot * 600 + 300 + ft],     sq0);
        atomicAdd(&part1[slot * 600 + 300 + ft + 1], sq1);
    }
}

// ---------- reduce partials -> per-feature affine (a, c) ----------
__global__ void stats_finalize(const float* __restrict__ part,
                               const float* __restrict__ g,
                               const float* __restrict__ be,
                               float invCnt, float* __restrict__ ac)
{
    const int t = threadIdx.x;
    if (t >= 300) return;
    float sum = 0.f, sq = 0.f;
    for (int p = 0; p < NPART; ++p) {
        sum += part[p * 600 + t];
        sq  += part[p * 600 + 300 + t];
    }
    const float mean = sum * invCnt;
    const float var = fmaxf(sq * invCnt - mean * mean, 0.f);
    const float inv = rsqrtf(var + 1e-5f);
    const float a = g[t] * inv;
    ac[t] = a;
    ac[300 + t] = be[t] - mean * a;
}

// ---------- decode zbuf -> Ab2 bf16 [N_cur][320] zero-padded ----------
__global__ void agg_finalize(const unsigned* __restrict__ zbuf,
                             const float* __restrict__ ac1,
                             bf16_t* __restrict__ Ab2)
{
    const int t = threadIdx.x;   // 320 threads
    float v = 0.f;
    if (t < 300) {
        const unsigned u = zbuf[(long)blockIdx.x * 320 + t];
        if (u != 0u) v = fabsf(ac1[t]) * dec_f32(u) + ac1[300 + t];
    }
    Ab2[(long)blockIdx.x * 320 + t] = (bf16_t)v;
}

// ---------- apply BN2 affine to d_out in place ----------
__global__ void finalize_out(float* __restrict__ out,
                             const float* __restrict__ ac2)
{
    const int t = threadIdx.x;
    if (t >= 300) return;
    const long i = (long)blockIdx.x * 300 + t;
    out[i] = ac2[t] * out[i] + ac2[300 + t];
}

extern "C" void kernel_launch(void* const* d_in, const int* in_sizes, int n_in,
                              void* d_out, int out_size, void* d_ws, size_t ws_size,
                              hipStream_t stream)
{
    const float* last_coors    = (const float*)d_in[0];
    const float* last_features = (const float*)d_in[1];
    const float* cur_coors     = (const float*)d_in[2];
    const int*   cur_idx       = (const int*)d_in[3];
    const int*   last_idx      = (const int*)d_in[4];
    const float* W1  = (const float*)d_in[5];
    const float* b1  = (const float*)d_in[6];
    const float* g1  = (const float*)d_in[7];
    const float* be1 = (const float*)d_in[8];
    const float* W2  = (const float*)d_in[9];
    const float* b2  = (const float*)d_in[10];
    const float* g2  = (const float*)d_in[11];
    const float* be2 = (const float*)d_in[12];
    float* out = (float*)d_out;

    const int N_last = in_sizes[0] / 3;
    const int N_cur  = in_sizes[2] / 3;
    const int E      = in_sizes[3];

    const int nb1 = (N_cur + SB - 1) / SB;

    // ---- workspace (aliased regions) ----
    char* ws = (char*)d_ws;
    size_t off = 0;
    // region0: Gb (N_last x 320 bf16) -> later Ab2 (N_cur x 320 bf16)
    const size_t sz_r0 = (size_t)N_last * 320 * 2;
    bf16_t* Gb  = (bf16_t*)(ws + off);
    bf16_t* Ab2 = (bf16_t*)(ws + off);
    off += sz_r0; off = (off + 255) & ~(size_t)255;
    // region1: Alf (N_last x 320 bf16) -> later zbuf (N_cur x 320 u32)
    const size_t sz_alf = (size_t)N_last * 320 * 2;
    const size_t sz_zb  = (size_t)N_cur * 320 * 4;
    bf16_t* Alf = (bf16_t*)(ws + off);
    unsigned* zbuf = (unsigned*)(ws + off);
    off += (sz_alf > sz_zb ? sz_alf : sz_zb); off = (off + 255) & ~(size_t)255;
    int2* sorted = (int2*)(ws + off);  off += (size_t)E * 8;
    int* hist = (int*)(ws + off);      off += (size_t)nb1 * SB * 4;
    int* cnt  = (int*)(ws + off);      off += (size_t)nb1 * SB * 4;
    int* bsum = (int*)(ws + off);      off += 256 * 4;
    bf16_t* WT1 = (bf16_t*)(ws + off); off += (size_t)384 * 320 * 2;
    bf16_t* WT2 = (bf16_t*)(ws + off); off += (size_t)384 * 320 * 2;
    float* part1 = (float*)(ws + off); off += (size_t)NPART * 600 * 4;
    float* part2 = (float*)(ws + off); off += (size_t)NPART * 600 * 4;
    float* ac1   = (float*)(ws + off); off += 600 * 4;
    float* ac2   = (float*)(ws + off); off += 600 * 4;

    hipMemsetAsync(hist, 0, (size_t)nb1 * SB * 4, stream);
    hipMemsetAsync(part1, 0, (size_t)NPART * 600 * 4, stream);
    hipMemsetAsync(part2, 0, (size_t)NPART * 600 * 4, stream);

    // ---- counting sort of edges by cur_idx (independent of regions 0/1) ----
    hist_k<<<(E + 255) / 256, 256, 0, stream>>>(cur_idx, E, hist);
    scan_reduce<<<nb1, SB, 0, stream>>>(hist, N_cur, bsum);
    scan_top<<<1, SB, 0, stream>>>(bsum, nb1);
    scan_final<<<nb1, SB, 0, stream>>>(hist, N_cur, bsum, cnt);
    scatter_k<<<(E + 255) / 256, 256, 0, stream>>>(cur_idx, last_idx, E, cnt, sorted);
    // cnt is now the per-segment END offset array

    // ---- weights + A conversion ----
    pack_wt<<<480, 256, 0, stream>>>(W1, WT1);
    pack_wt<<<480, 256, 0, stream>>>(W2, WT2);
    cvt_lf<<<((N_last * 40) + 255) / 256, 256, 0, stream>>>(last_features, Alf, N_last);

    // G = last_features @ W1[:300] + b1  (bf16 MFMA; reads Alf, writes Gb [M][320])
    dim3 gridG((N_last + 127) / 128, 2);
    gemm_mfma<0><<<gridG, 256, 0, stream>>>(Alf, N_last, WT1, b1, Gb, nullptr, nullptr);

    // zbuf overwrites Alf (stream-ordered after gemm0)
    hipMemsetAsync(zbuf, 0, sz_zb, stream);

    // edge pass: one block per SEGB segments
    const int nSB = (N_cur + SEGB - 1) / SEGB;
    edge_pass<<<nSB, 320, 0, stream>>>(Gb, last_coors, cur_coors, sorted, cnt,
                                       W1 + 300 * 300, g1, zbuf, part1, N_cur);

    stats_finalize<<<1, 320, 0, stream>>>(part1, g1, be1, 1.0f / (float)E, ac1);
    // Ab2 overwrites Gb (Gb consumed by edge_pass)
    agg_finalize<<<N_cur, 320, 0, stream>>>(zbuf, ac1, Ab2);

    // out_pre = ReLU(agg @ W2 + b2), stats2 partials (bf16 MFMA)
    dim3 grid2((N_cur + 127) / 128, 2);
    gemm_mfma<1><<<grid2, 256, 0, stream>>>(Ab2, N_cur, WT2, b2, nullptr, out, part2);

    stats_finalize<<<1, 320, 0, stream>>>(part2, g2, be2, 1.0f / (float)N_cur, ac2);
    finalize_out<<<N_cur, 320, 0, stream>>>(out, ac2);
}